// Round 1
// baseline (66.778 us; speedup 1.0000x reference)
//
#include <hip/hip_runtime.h>

#define DFEAT 64

// ---------------------------------------------------------------------------
// Kernel 1: per-edge dedupe via adjacency bitmap + column-degree count.
// Exactly one edge instance per unique (s,t) gets flags[e]=1.
// ---------------------------------------------------------------------------
__global__ void edge_mark_kernel(const int* __restrict__ ei,
                                 unsigned int* __restrict__ bitmap,
                                 int* __restrict__ deg,
                                 unsigned char* __restrict__ flags,
                                 int nE, int nN) {
    int e = blockIdx.x * blockDim.x + threadIdx.x;
    if (e >= nE) return;
    int s = ei[e];          // edge_index[0][e]
    int t = ei[nE + e];     // edge_index[1][e]
    long long pos = (long long)s * nN + t;   // adj[s][t]
    unsigned int w = (unsigned int)(pos >> 5);
    unsigned int bit = 1u << ((unsigned int)pos & 31u);
    unsigned int old = atomicOr(&bitmap[w], bit);
    unsigned char fresh = (old & bit) ? 0 : 1;
    flags[e] = fresh;
    if (fresh) atomicAdd(&deg[t], 1);        // column sum of adj
}

// ---------------------------------------------------------------------------
// Kernel 2: d[j] = rsqrt(deg[j]+1)  (the +1 is the self-loop from +I);
//           y[j][:] = d[j] * x[j][:]
// ---------------------------------------------------------------------------
__global__ void scale_x_kernel(const float* __restrict__ x,
                               const int* __restrict__ deg,
                               float* __restrict__ dvec,
                               float* __restrict__ y,
                               int total) {
    int i = blockIdx.x * blockDim.x + threadIdx.x;
    if (i >= total) return;
    int node = i >> 6;
    float dv = rsqrtf((float)(deg[node] + 1));
    if ((i & 63) == 0) dvec[node] = dv;
    y[i] = dv * x[i];
}

// ---------------------------------------------------------------------------
// Kernel 3: scatter z[s][:] += y[t][:] for each unique edge.
// One 64-lane wave per edge: lane k handles feature k. flags[e] is
// wave-uniform so no divergence; loads and atomics are fully coalesced.
// ---------------------------------------------------------------------------
__global__ void edge_scatter_kernel(const int* __restrict__ ei,
                                    const unsigned char* __restrict__ flags,
                                    const float* __restrict__ y,
                                    float* __restrict__ z,
                                    int nE) {
    int idx = blockIdx.x * blockDim.x + threadIdx.x;
    int e = idx >> 6;
    if (e >= nE) return;
    if (!flags[e]) return;
    int k = idx & 63;
    int s = ei[e];
    int t = ei[nE + e];
    atomicAdd(&z[(long long)s * DFEAT + k], y[(long long)t * DFEAT + k]);
}

// ---------------------------------------------------------------------------
// Kernel 4: h[i] = d[i]*(z[i] + y[i])  (the +y[i] is the self-loop A[i][i]
// contribution from +I; a self-loop EDGE was already scattered on top, giving
// the reference's A[i][i]=2 behavior). Then out[i] = h[i] @ W^T + b.
// 4 nodes per 256-thread block; W staged transposed in padded LDS.
// ---------------------------------------------------------------------------
__global__ void finalize_kernel(const float* __restrict__ y,
                                const float* __restrict__ z,
                                const float* __restrict__ dvec,
                                const float* __restrict__ W,
                                const float* __restrict__ b,
                                float* __restrict__ out) {
    __shared__ float hsm[4][DFEAT];
    __shared__ float Wt[DFEAT][DFEAT + 1];   // +1 pad: conflict-free reads
    int tid = threadIdx.x;

    // Stage W transposed: Wt[k][o] = W[o][k]
    for (int idx = tid; idx < DFEAT * DFEAT; idx += 256) {
        int o = idx >> 6, k = idx & 63;
        Wt[k][o] = W[idx];
    }

    int sub = tid >> 6;                 // which of the 4 nodes
    int o   = tid & 63;                 // output feature
    int node = blockIdx.x * 4 + sub;
    float dv = dvec[node];
    long long base = (long long)node * DFEAT;
    float h = dv * (z[base + o] + y[base + o]);
    hsm[sub][o] = h;
    __syncthreads();

    float acc = b[o];
#pragma unroll 8
    for (int k = 0; k < DFEAT; ++k)
        acc = fmaf(hsm[sub][k], Wt[k][o], acc);   // hsm: broadcast; Wt: no conflict
    out[base + o] = acc;
}

// ---------------------------------------------------------------------------
extern "C" void kernel_launch(void* const* d_in, const int* in_sizes, int n_in,
                              void* d_out, int out_size, void* d_ws, size_t ws_size,
                              hipStream_t stream) {
    const float* x  = (const float*)d_in[0];
    const int*   ei = (const int*)d_in[1];
    const float* W  = (const float*)d_in[2];
    const float* b  = (const float*)d_in[3];
    float* out = (float*)d_out;

    int nN = in_sizes[0] / DFEAT;   // 8192
    int nE = in_sizes[1] / 2;       // 131072

    // Workspace layout (bytes):
    //   [bitmap nN*nN/8][deg nN*4][z nN*64*4][d nN*4][y nN*64*4][flags nE]
    char* ws = (char*)d_ws;
    size_t bitmap_bytes = (size_t)nN * (size_t)nN / 8;   // 8 MB
    size_t off = 0;
    unsigned int* bitmap = (unsigned int*)(ws + off); off += bitmap_bytes;
    int*   deg  = (int*)(ws + off);   off += (size_t)nN * 4;
    float* z    = (float*)(ws + off); off += (size_t)nN * DFEAT * 4;
    size_t clear_bytes = off;         // bitmap + deg + z must be zeroed each call
    float* dvec = (float*)(ws + off); off += (size_t)nN * 4;
    float* y    = (float*)(ws + off); off += (size_t)nN * DFEAT * 4;
    unsigned char* flags = (unsigned char*)(ws + off); off += (size_t)nE;

    hipMemsetAsync(ws, 0, clear_bytes, stream);

    edge_mark_kernel<<<(nE + 255) / 256, 256, 0, stream>>>(ei, bitmap, deg, flags, nE, nN);

    int total = nN * DFEAT;
    scale_x_kernel<<<(total + 255) / 256, 256, 0, stream>>>(x, deg, dvec, y, total);

    edge_scatter_kernel<<<(nE * DFEAT) / 256, 256, 0, stream>>>(ei, flags, y, z, nE);

    finalize_kernel<<<nN / 4, 256, 0, stream>>>(y, z, dvec, W, b, out);
}

// Round 2
// 66.399 us; speedup vs baseline: 1.0057x; 1.0057x over previous
//
#include <hip/hip_runtime.h>

#define DFEAT 64

// ---------------------------------------------------------------------------
// Kernel 0: clear exactly the bitmap words edges will touch (instead of an
// 8 MB memset — 40 µs of fillBufferAligned last round), plus the 32 KB deg
// array. Racy duplicate stores of 0 to the same word are benign; the kernel
// boundary orders them before edge_mark's atomicOr.
// ---------------------------------------------------------------------------
__global__ void clear_touched_kernel(const int* __restrict__ ei,
                                     unsigned int* __restrict__ bitmap,
                                     int* __restrict__ deg,
                                     int nE, int nN) {
    int i = blockIdx.x * blockDim.x + threadIdx.x;
    if (i < nE) {
        int s = ei[i];
        int t = ei[nE + i];
        long long pos = (long long)s * nN + t;
        bitmap[(unsigned int)(pos >> 5)] = 0u;
    }
    if (i < nN) deg[i] = 0;
}

// ---------------------------------------------------------------------------
// Kernel 1: per-edge dedupe via adjacency bitmap + column-degree count.
// Exactly one edge instance per unique (s,t) gets flags[e]=1.
// ---------------------------------------------------------------------------
__global__ void edge_mark_kernel(const int* __restrict__ ei,
                                 unsigned int* __restrict__ bitmap,
                                 int* __restrict__ deg,
                                 unsigned char* __restrict__ flags,
                                 int nE, int nN) {
    int e = blockIdx.x * blockDim.x + threadIdx.x;
    if (e >= nE) return;
    int s = ei[e];          // edge_index[0][e]
    int t = ei[nE + e];     // edge_index[1][e]
    long long pos = (long long)s * nN + t;   // adj[s][t]
    unsigned int w = (unsigned int)(pos >> 5);
    unsigned int bit = 1u << ((unsigned int)pos & 31u);
    unsigned int old = atomicOr(&bitmap[w], bit);
    unsigned char fresh = (old & bit) ? 0 : 1;
    flags[e] = fresh;
    if (fresh) atomicAdd(&deg[t], 1);        // column sum of adj
}

// ---------------------------------------------------------------------------
// Kernel 2: d[j] = rsqrt(deg[j]+1)  (+1 = self-loop from +I);
//           y[j][:] = d[j]*x[j][:];  z[j][:] = y[j][:]  (z init = the +I
//           self contribution, so no z memset and finalize reads only z).
// float4-vectorized: thread handles 4 floats; 16 threads per node.
// ---------------------------------------------------------------------------
__global__ void scale_x_kernel(const float* __restrict__ x,
                               const int* __restrict__ deg,
                               float* __restrict__ dvec,
                               float* __restrict__ y,
                               float* __restrict__ z,
                               int total4) {
    int i = blockIdx.x * blockDim.x + threadIdx.x;
    if (i >= total4) return;
    int node = i >> 4;                       // 16 float4 per 64-feat node
    float dv = rsqrtf((float)(deg[node] + 1));
    if ((i & 15) == 0) dvec[node] = dv;
    float4 v = ((const float4*)x)[i];
    v.x *= dv; v.y *= dv; v.z *= dv; v.w *= dv;
    ((float4*)y)[i] = v;
    ((float4*)z)[i] = v;
}

// ---------------------------------------------------------------------------
// Kernel 3: scatter z[s][:] += y[t][:] for each unique edge.
// One 64-lane wave per edge: lane k handles feature k. flags[e] is
// wave-uniform so no divergence; loads and atomics are fully coalesced.
// ---------------------------------------------------------------------------
__global__ void edge_scatter_kernel(const int* __restrict__ ei,
                                    const unsigned char* __restrict__ flags,
                                    const float* __restrict__ y,
                                    float* __restrict__ z,
                                    int nE) {
    int idx = blockIdx.x * blockDim.x + threadIdx.x;
    int e = idx >> 6;
    if (e >= nE) return;
    if (!flags[e]) return;
    int k = idx & 63;
    int s = ei[e];
    int t = ei[nE + e];
    atomicAdd(&z[(long long)s * DFEAT + k], y[(long long)t * DFEAT + k]);
}

// ---------------------------------------------------------------------------
// Kernel 4: h[i] = d[i]*z[i]; out[i] = h[i] @ W^T + b.
// 4 nodes per 256-thread block; W staged transposed in padded LDS.
// ---------------------------------------------------------------------------
__global__ void finalize_kernel(const float* __restrict__ z,
                                const float* __restrict__ dvec,
                                const float* __restrict__ W,
                                const float* __restrict__ b,
                                float* __restrict__ out) {
    __shared__ float hsm[4][DFEAT];
    __shared__ float Wt[DFEAT][DFEAT + 1];   // +1 pad: conflict-free reads
    int tid = threadIdx.x;

    // Stage W transposed: Wt[k][o] = W[o][k]
    for (int idx = tid; idx < DFEAT * DFEAT; idx += 256) {
        int o = idx >> 6, k = idx & 63;
        Wt[k][o] = W[idx];
    }

    int sub = tid >> 6;                 // which of the 4 nodes
    int o   = tid & 63;                 // output feature
    int node = blockIdx.x * 4 + sub;
    float dv = dvec[node];
    long long base = (long long)node * DFEAT;
    float h = dv * z[base + o];
    hsm[sub][o] = h;
    __syncthreads();

    float acc = b[o];
#pragma unroll 8
    for (int k = 0; k < DFEAT; ++k)
        acc = fmaf(hsm[sub][k], Wt[k][o], acc);   // hsm: broadcast; Wt: no conflict
    out[base + o] = acc;
}

// ---------------------------------------------------------------------------
extern "C" void kernel_launch(void* const* d_in, const int* in_sizes, int n_in,
                              void* d_out, int out_size, void* d_ws, size_t ws_size,
                              hipStream_t stream) {
    const float* x  = (const float*)d_in[0];
    const int*   ei = (const int*)d_in[1];
    const float* W  = (const float*)d_in[2];
    const float* b  = (const float*)d_in[3];
    float* out = (float*)d_out;

    int nN = in_sizes[0] / DFEAT;   // 8192
    int nE = in_sizes[1] / 2;       // 131072

    // Workspace layout (bytes):
    //   [bitmap nN*nN/8][deg nN*4][z nN*64*4][d nN*4][y nN*64*4][flags nE]
    char* ws = (char*)d_ws;
    size_t bitmap_bytes = (size_t)nN * (size_t)nN / 8;   // 8 MB
    size_t off = 0;
    unsigned int* bitmap = (unsigned int*)(ws + off); off += bitmap_bytes;
    int*   deg  = (int*)(ws + off);   off += (size_t)nN * 4;
    float* z    = (float*)(ws + off); off += (size_t)nN * DFEAT * 4;
    float* dvec = (float*)(ws + off); off += (size_t)nN * 4;
    float* y    = (float*)(ws + off); off += (size_t)nN * DFEAT * 4;
    unsigned char* flags = (unsigned char*)(ws + off); off += (size_t)nE;

    clear_touched_kernel<<<(nE + 255) / 256, 256, 0, stream>>>(ei, bitmap, deg, nE, nN);

    edge_mark_kernel<<<(nE + 255) / 256, 256, 0, stream>>>(ei, bitmap, deg, flags, nE, nN);

    int total4 = nN * DFEAT / 4;
    scale_x_kernel<<<(total4 + 255) / 256, 256, 0, stream>>>(x, deg, dvec, y, z, total4);

    edge_scatter_kernel<<<(nE * DFEAT) / 256, 256, 0, stream>>>(ei, flags, y, z, nE);

    finalize_kernel<<<nN / 4, 256, 0, stream>>>(z, dvec, W, b, out);
}